// Round 8
// baseline (348.366 us; speedup 1.0000x reference)
//
#include <hip/hip_runtime.h>
#include <cmath>

// ---------------------------------------------------------------------------
// NonLocalBlock round 7 (resubmit): attn restructure.
//  - S computed transposed (A=phi, B=theta) -> lane owns one n-row: softmax is
//    15 in-lane fmax + 2 cross-lane shuffles; rescale is 1 scalar/lane.
//  - theta fragments in registers (reused over all 16 m-tiles): Tl LDS gone.
//  - P redistributed to PV B-fragments via shuffles in the 4-lane group
//    (lanes l15, +16, +32, +48 hold the 64 m of one n): Pl LDS gone.
//  - 6 barriers/m-tile (was 17); LDS 51 KB -> 3 blocks/CU.
// proj/out/xt/wconv unchanged from the verified round-6 kernel.
// ---------------------------------------------------------------------------

#define B_  8
#define C_  512
#define CI_ 256
#define N_  4096   // 64*64
#define M_  1024   // 32*32

typedef _Float16 half8 __attribute__((ext_vector_type(8)));
typedef _Float16 half4 __attribute__((ext_vector_type(4)));
typedef float    f32x4 __attribute__((ext_vector_type(4)));

static __device__ __forceinline__ unsigned pkh(float a, float b) {
    _Float16 ha = (_Float16)a, hb = (_Float16)b;
    unsigned short ua = __builtin_bit_cast(unsigned short, ha);
    unsigned short ub = __builtin_bit_cast(unsigned short, hb);
    return (unsigned)ua | ((unsigned)ub << 16);
}

// ===========================================================================
// K0a: weights -> fp16.  wAll rows: [0,256)=g, [256,512)=theta, [512,768)=phi
// ===========================================================================
__global__ __launch_bounds__(256) void wconv_kernel(
    const float* __restrict__ g_w, const float* __restrict__ th_w,
    const float* __restrict__ ph_w, const float* __restrict__ w_w,
    _Float16* __restrict__ wAll, _Float16* __restrict__ w16)
{
    const int i = blockIdx.x * 256 + threadIdx.x;
    if (i < 768 * 512) {
        const int o = i >> 9, c = i & 511;
        const float v = (o < 256) ? g_w[o * 512 + c]
                      : (o < 512) ? th_w[(o - 256) * 512 + c]
                                  : ph_w[(o - 512) * 512 + c];
        wAll[i] = (_Float16)v;
    } else {
        const int j = i - 768 * 512;
        w16[j] = (_Float16)w_w[j];
    }
}

// ===========================================================================
// K0b: xT[b][n][c] f16 from x[b][c][n] f32.  Tile [64c][64n] via LDS.
// ===========================================================================
__global__ __launch_bounds__(256) void xt_kernel(
    const float* __restrict__ x, _Float16* __restrict__ xT)
{
    __shared__ float Ls[64][68];
    const int t = threadIdx.x;
    const int n0 = blockIdx.x * 64, c0 = blockIdx.y * 64, b = blockIdx.z;

    const int row = t >> 4, coln = (t & 15) * 4;
    #pragma unroll
    for (int p = 0; p < 4; ++p) {
        const int c = p * 16 + row;
        *(float4*)&Ls[c][coln] = *(const float4*)&x[((size_t)b * C_ + c0 + c) * N_ + n0 + coln];
    }
    __syncthreads();
    const int nr = t >> 2, cq = (t & 3) * 16;
    _Float16 hv[16];
    #pragma unroll
    for (int j = 0; j < 16; ++j) hv[j] = (_Float16)Ls[cq + j][nr];
    _Float16* dst = &xT[((size_t)b * N_ + n0 + nr) * C_ + c0 + cq];
    *(half8*)&dst[0] = *(half8*)&hv[0];
    *(half8*)&dst[8] = *(half8*)&hv[8];
}

// ===========================================================================
// K1: proj GEMM on MFMA (unchanged from round 6).
// ===========================================================================
__global__ __launch_bounds__(256) void proj_kernel(
    const _Float16* __restrict__ xT, const _Float16* __restrict__ wAll,
    const float* __restrict__ g_b, const float* __restrict__ th_b,
    const float* __restrict__ ph_b,
    _Float16* __restrict__ thT, _Float16* __restrict__ phT, _Float16* __restrict__ g16)
{
    __shared__ __align__(16) char smem[27648];
    _Float16 (*Ws)[72] = (_Float16(*)[72])smem;            // 64 x 72  = 9216 B
    _Float16 (*Xs)[72] = (_Float16(*)[72])(smem + 9216);   // 128 x 72 = 18432 B
    _Float16 (*Yt)[72] = (_Float16(*)[72])smem;            // theta epi: 128 x 72
    _Float16 (*Pp)[72] = (_Float16(*)[72])smem;            // phi epi:   32 x 72
    _Float16 (*Pg)[40] = (_Float16(*)[40])smem;            // g epi:     64 x 40

    const int t = threadIdx.x;
    const int w = t >> 6, l = t & 63, l15 = l & 15, lg = l >> 4;
    const int bx = blockIdx.x, rt = blockIdx.y, b = blockIdx.z;
    const int r0 = rt * 64, n0 = bx * 128;

    f32x4 acc[8];
    #pragma unroll
    for (int f = 0; f < 8; ++f) acc[f] = (f32x4){0.f, 0.f, 0.f, 0.f};

    const int warow = t >> 2, wakq = (t & 3) * 16;
    const int xrow = t >> 1,  xkq = (t & 1) * 32;

    #pragma unroll 1
    for (int k0 = 0; k0 < C_; k0 += 64) {
        __syncthreads();
        {
            const _Float16* src = &wAll[(size_t)(r0 + warow) * C_ + k0 + wakq];
            *(half8*)&Ws[warow][wakq]     = *(const half8*)&src[0];
            *(half8*)&Ws[warow][wakq + 8] = *(const half8*)&src[8];
            const _Float16* xs = &xT[((size_t)b * N_ + n0 + xrow) * C_ + k0 + xkq];
            *(half8*)&Xs[xrow][xkq]      = *(const half8*)&xs[0];
            *(half8*)&Xs[xrow][xkq + 8]  = *(const half8*)&xs[8];
            *(half8*)&Xs[xrow][xkq + 16] = *(const half8*)&xs[16];
            *(half8*)&Xs[xrow][xkq + 24] = *(const half8*)&xs[24];
        }
        __syncthreads();
        #pragma unroll
        for (int ks = 0; ks < 2; ++ks) {
            half8 a = *(half8*)&Ws[w * 16 + l15][ks * 32 + lg * 8];
            #pragma unroll
            for (int f = 0; f < 8; ++f) {
                half8 bb = *(half8*)&Xs[f * 16 + l15][ks * 32 + lg * 8];
                acc[f] = __builtin_amdgcn_mfma_f32_16x16x32_f16(a, bb, acc[f], 0, 0, 0);
            }
        }
    }

    {
        const float* Bp = (rt < 4) ? g_b : (rt < 8) ? th_b : ph_b;
        const int coff = (rt < 4) ? 0 : (rt < 8) ? 256 : 512;
        float bias[4];
        #pragma unroll
        for (int r = 0; r < 4; ++r) bias[r] = Bp[r0 - coff + w * 16 + lg * 4 + r];
        #pragma unroll
        for (int f = 0; f < 8; ++f)
            #pragma unroll
            for (int r = 0; r < 4; ++r) acc[f][r] += bias[r];
    }

    if (rt >= 4 && rt < 8) {
        const int c0 = r0 - 256;
        __syncthreads();
        #pragma unroll
        for (int f = 0; f < 8; ++f) {
            half4 hv = { (_Float16)acc[f][0], (_Float16)acc[f][1],
                         (_Float16)acc[f][2], (_Float16)acc[f][3] };
            *(half4*)&Yt[f * 16 + l15][w * 16 + lg * 4] = hv;
        }
        __syncthreads();
        const int nr = t >> 1, oq = (t & 1) * 32;
        _Float16* dst = &thT[((size_t)b * N_ + n0 + nr) * CI_ + c0 + oq];
        #pragma unroll
        for (int j = 0; j < 4; ++j)
            *(half8*)&dst[j * 8] = *(half8*)&Yt[nr][oq + j * 8];
    } else {
        float pool[4][4];
        #pragma unroll
        for (int f = 0; f < 4; ++f)
            #pragma unroll
            for (int r = 0; r < 4; ++r) {
                const float v0 = acc[f][r], v1 = acc[f + 4][r];
                const float h0 = fmaxf(v0, __shfl_xor(v0, 1));
                const float h1 = fmaxf(v1, __shfl_xor(v1, 1));
                pool[f][r] = fmaxf(h0, h1);   // valid on even l15
            }
        __syncthreads();
        const bool isphi = (rt >= 8);
        const int c0 = isphi ? r0 - 512 : r0;
        if ((l15 & 1) == 0) {
            const int Wl = l15 >> 1;
            if (isphi) {
                #pragma unroll
                for (int f = 0; f < 4; ++f) {
                    half4 hv = { (_Float16)pool[f][0], (_Float16)pool[f][1],
                                 (_Float16)pool[f][2], (_Float16)pool[f][3] };
                    *(half4*)&Pp[f * 8 + Wl][w * 16 + lg * 4] = hv;
                }
            } else {
                #pragma unroll
                for (int f = 0; f < 4; ++f)
                    #pragma unroll
                    for (int r = 0; r < 4; ++r)
                        Pg[w * 16 + lg * 4 + r][f * 8 + Wl] = (_Float16)pool[f][r];
            }
        }
        __syncthreads();
        if (isphi) {
            const int row = t >> 3, cqq = (t & 7) * 8;
            *(half8*)&phT[((size_t)b * M_ + bx * 32 + row) * CI_ + c0 + cqq] =
                *(half8*)&Pp[row][cqq];
        } else {
            const int row = t >> 2, mq = (t & 3) * 8;
            *(half8*)&g16[((size_t)b * CI_ + r0 + row) * M_ + bx * 32 + mq] =
                *(half8*)&Pg[row][mq];
        }
    }
}

// ===========================================================================
// K2: flash attention, restructured.
// Block: 4 waves, QBLK=64 (lane owns n = n0 + w*16 + l15).
// S^T via mfma(A=phi, B=theta-regs): sf[mf][r] = S[n][m=mf*16+lg*4+r].
// P redistributed by shuffles within lane group {l15,+16,+32,+48}.
// PV: yacc[q][r] = Y[ci=q*16+lg*4+r][n].
// LDS: Ph 64x264 (33792) + Gl 128x72 (18432) = 52224 B -> 3 blocks/CU.
// ===========================================================================
__global__ __launch_bounds__(256, 3) void attn_kernel(
    const _Float16* __restrict__ thT, const _Float16* __restrict__ phT,
    const _Float16* __restrict__ g16, _Float16* __restrict__ y16)
{
    __shared__ __align__(16) char smem[52224];
    _Float16 (*Ph)[264] = (_Float16(*)[264])smem;            // 64 x 264
    _Float16 (*Gl)[72]  = (_Float16(*)[72])(smem + 33792);   // 128 x 72

    const int t = threadIdx.x;
    const int w = t >> 6, l = t & 63;
    const int l15 = l & 15, lg = l >> 4;
    const int n0 = blockIdx.x * 64;
    const int b  = blockIdx.y;
    const int n  = n0 + w * 16 + l15;     // this lane's query row

    // ---- theta fragments in registers: ta[kc] = thT[n][kc*32 + lg*8 ..+7] ----
    half8 ta[8];
    {
        const _Float16* src = &thT[((size_t)b * N_ + n) * CI_ + lg * 8];
        #pragma unroll
        for (int kc = 0; kc < 8; ++kc)
            ta[kc] = *(const half8*)&src[kc * 32];
    }

    f32x4 yacc[16];
    #pragma unroll
    for (int i = 0; i < 16; ++i) yacc[i] = (f32x4){0.f, 0.f, 0.f, 0.f};
    float m_run = -INFINITY, l_run = 0.f;

    const int phrow = t >> 2, phseg = (t & 3) * 64;   // phi staging
    const int glrow = t >> 1, glseg = (t & 1) * 32;   // g staging

    const int baseA = ((lg & 1) * 2) * 16 + l15;      // src lanes for P redistribution
    const int baseB = baseA + 16;
    const bool hi = ((lg >> 1) & 1) != 0;

    #pragma unroll 1
    for (int mt = 0; mt < 16; ++mt) {
        const int m0 = mt * 64;

        // ---- stage phi tile [64 m][256 c] ----
        __syncthreads();
        {
            const _Float16* src = &phT[((size_t)b * M_ + m0 + phrow) * CI_ + phseg];
            #pragma unroll
            for (int j = 0; j < 8; ++j)
                *(half8*)&Ph[phrow][phseg + j * 8] = *(const half8*)&src[j * 8];
        }
        __syncthreads();

        // ---- S^T: sf[mf][r] = S[n][m=mf*16+lg*4+r] ----
        f32x4 sf[4];
        #pragma unroll
        for (int i = 0; i < 4; ++i) sf[i] = (f32x4){0.f, 0.f, 0.f, 0.f};
        #pragma unroll
        for (int kc = 0; kc < 8; ++kc) {
            #pragma unroll
            for (int mf = 0; mf < 4; ++mf) {
                half8 a = *(half8*)&Ph[mf * 16 + l15][kc * 32 + lg * 8];
                sf[mf] = __builtin_amdgcn_mfma_f32_16x16x32_f16(a, ta[kc], sf[mf], 0, 0, 0);
            }
        }

        // ---- online softmax (lane owns one n; group of 4 lanes holds 64 m) ----
        float mx = sf[0][0];
        #pragma unroll
        for (int mf = 0; mf < 4; ++mf)
            #pragma unroll
            for (int r = 0; r < 4; ++r) mx = fmaxf(mx, sf[mf][r]);
        mx = fmaxf(mx, __shfl_xor(mx, 16, 64));
        mx = fmaxf(mx, __shfl_xor(mx, 32, 64));
        const float mnew = fmaxf(m_run, mx);
        const float scl = __expf(m_run - mnew);
        float s = 0.f;
        unsigned u0[4], u1[4];
        #pragma unroll
        for (int mf = 0; mf < 4; ++mf) {
            const float p0 = __expf(sf[mf][0] - mnew);
            const float p1 = __expf(sf[mf][1] - mnew);
            const float p2 = __expf(sf[mf][2] - mnew);
            const float p3 = __expf(sf[mf][3] - mnew);
            s += (p0 + p1) + (p2 + p3);
            u0[mf] = pkh(p0, p1);
            u1[mf] = pkh(p2, p3);
        }
        s += __shfl_xor(s, 16, 64);
        s += __shfl_xor(s, 32, 64);
        l_run = l_run * scl + s;
        m_run = mnew;
        #pragma unroll
        for (int i = 0; i < 16; ++i) {
            yacc[i][0] *= scl; yacc[i][1] *= scl;
            yacc[i][2] *= scl; yacc[i][3] *= scl;
        }

        // ---- redistribute P into PV B-fragments (no LDS) ----
        // dest lane (lg): needs m = ks*32 + lg*8 + i ; sources are the two lanes
        // slg0=(lg&1)*2, slg1=slg0+1 of its 4-lane group; mf_sel = 2ks + (lg>>1).
        half8 pb[2];
        #pragma unroll
        for (int ks = 0; ks < 2; ++ks) {
            const unsigned a0 = __shfl(u0[2 * ks],     baseA, 64);
            const unsigned a1 = __shfl(u1[2 * ks],     baseA, 64);
            const unsigned c0 = __shfl(u0[2 * ks + 1], baseA, 64);
            const unsigned c1 = __shfl(u1[2 * ks + 1], baseA, 64);
            const unsigned b0 = __shfl(u0[2 * ks],     baseB, 64);
            const unsigned b1 = __shfl(u1[2 * ks],     baseB, 64);
            const unsigned d0 = __shfl(u0[2 * ks + 1], baseB, 64);
            const unsigned d1 = __shfl(u1[2 * ks + 1], baseB, 64);
            union { unsigned u[4]; half8 h; } cv;
            cv.u[0] = hi ? c0 : a0;
            cv.u[1] = hi ? c1 : a1;
            cv.u[2] = hi ? d0 : b0;
            cv.u[3] = hi ? d1 : b1;
            pb[ks] = cv.h;
        }

        // ---- PV: Y[ci][n] += G[ci][m] * P^T[m][n], two 128-ci chunks ----
        #pragma unroll
        for (int ch = 0; ch < 2; ++ch) {
            __syncthreads();
            {
                const _Float16* src = &g16[((size_t)b * CI_ + ch * 128 + glrow) * M_ + m0 + glseg];
                #pragma unroll
                for (int j = 0; j < 4; ++j)
                    *(half8*)&Gl[glrow][glseg + j * 8] = *(const half8*)&src[j * 8];
            }
            __syncthreads();
            #pragma unroll
            for (int cf = 0; cf < 8; ++cf) {
                half8 a0 = *(half8*)&Gl[cf * 16 + l15][lg * 8];
                half8 a1 = *(half8*)&Gl[cf * 16 + l15][32 + lg * 8];
                yacc[ch * 8 + cf] = __builtin_amdgcn_mfma_f32_16x16x32_f16(a0, pb[0], yacc[ch * 8 + cf], 0, 0, 0);
                yacc[ch * 8 + cf] = __builtin_amdgcn_mfma_f32_16x16x32_f16(a1, pb[1], yacc[ch * 8 + cf], 0, 0, 0);
            }
        }
    }

    // ---- epilogue: y16[b][n][ci], lane writes its n-row (half4 per ci-frag) ----
    const float linv = 1.f / l_run;
    _Float16* dst = &y16[((size_t)b * N_ + n) * CI_];
    #pragma unroll
    for (int q = 0; q < 16; ++q) {
        half4 hv = { (_Float16)(yacc[q][0] * linv), (_Float16)(yacc[q][1] * linv),
                     (_Float16)(yacc[q][2] * linv), (_Float16)(yacc[q][3] * linv) };
        *(half4*)&dst[q * 16 + lg * 4] = hv;
    }
}

// ===========================================================================
// K3: out conv on MFMA + bias + BN + residual (unchanged from round 6).
// ===========================================================================
__global__ __launch_bounds__(256) void out_kernel(
    const _Float16* __restrict__ y16, const _Float16* __restrict__ w16,
    const float* __restrict__ w_b,
    const float* __restrict__ bn_g, const float* __restrict__ bn_b,
    const float* __restrict__ bn_m, const float* __restrict__ bn_v,
    const float* __restrict__ x, float* __restrict__ out)
{
    __shared__ __align__(16) char smem[33792];
    _Float16 (*Ws)[72] = (_Float16(*)[72])smem;            // 64 x 72
    _Float16 (*Ys)[72] = (_Float16(*)[72])(smem + 9216);   // 128 x 72
    float    (*Yt)[132] = (float(*)[132])smem;             // 64 x 132 f32 overlay

    const int t = threadIdx.x;
    const int w = t >> 6, l = t & 63, l15 = l & 15, lg = l >> 4;
    const int bx = blockIdx.x, by = blockIdx.y, b = blockIdx.z;
    const int r0 = by * 64, n0 = bx * 128;

    f32x4 acc[8];
    #pragma unroll
    for (int f = 0; f < 8; ++f) acc[f] = (f32x4){0.f, 0.f, 0.f, 0.f};

    const int warow = t >> 2, wakq = (t & 3) * 16;
    const int yrow = t >> 1,  ykq = (t & 1) * 32;

    #pragma unroll 1
    for (int k0 = 0; k0 < CI_; k0 += 64) {
        __syncthreads();
        {
            const _Float16* src = &w16[(size_t)(r0 + warow) * CI_ + k0 + wakq];
            *(half8*)&Ws[warow][wakq]     = *(const half8*)&src[0];
            *(half8*)&Ws[warow][wakq + 8] = *(const half8*)&src[8];
            const _Float16* ys = &y16[((size_t)b * N_ + n0 + yrow) * CI_ + k0 + ykq];
            *(half8*)&Ys[yrow][ykq]      = *(const half8*)&ys[0];
            *(half8*)&Ys[yrow][ykq + 8]  = *(const half8*)&ys[8];
            *(half8*)&Ys[yrow][ykq + 16] = *(const half8*)&ys[16];
            *(half8*)&Ys[yrow][ykq + 24] = *(const half8*)&ys[24];
        }
        __syncthreads();
        #pragma unroll
        for (int ks = 0; ks < 2; ++ks) {
            half8 a = *(half8*)&Ws[w * 16 + l15][ks * 32 + lg * 8];
            #pragma unroll
            for (int f = 0; f < 8; ++f) {
                half8 bb = *(half8*)&Ys[f * 16 + l15][ks * 32 + lg * 8];
                acc[f] = __builtin_amdgcn_mfma_f32_16x16x32_f16(a, bb, acc[f], 0, 0, 0);
            }
        }
    }

    float scp[4], shp[4];
    #pragma unroll
    for (int r = 0; r < 4; ++r) {
        const int c = r0 + w * 16 + lg * 4 + r;
        const float s = bn_g[c] * rsqrtf(bn_v[c] + 1e-5f);
        scp[r] = s;
        shp[r] = bn_b[c] + (w_b[c] - bn_m[c]) * s;
    }
    __syncthreads();
    #pragma unroll
    for (int f = 0; f < 8; ++f)
        #pragma unroll
        for (int r = 0; r < 4; ++r)
            Yt[w * 16 + lg * 4 + r][f * 16 + l15] = acc[f][r] * scp[r] + shp[r];
    __syncthreads();

    const int prow = t >> 5, nq = (t & 31) * 4;
    #pragma unroll
    for (int p = 0; p < 8; ++p) {
        const int row = p * 8 + prow;
        const size_t base = ((size_t)b * C_ + r0 + row) * N_ + n0 + nq;
        const float4 xr = *(const float4*)&x[base];
        float4 v = *(float4*)&Yt[row][nq];
        v.x += xr.x; v.y += xr.y; v.z += xr.z; v.w += xr.w;
        *(float4*)&out[base] = v;
    }
}

// ===========================================================================
extern "C" void kernel_launch(void* const* d_in, const int* in_sizes, int n_in,
                              void* d_out, int out_size, void* d_ws, size_t ws_size,
                              hipStream_t stream) {
    const float* x    = (const float*)d_in[0];
    const float* g_w  = (const float*)d_in[1];
    const float* g_b  = (const float*)d_in[2];
    const float* th_w = (const float*)d_in[3];
    const float* th_b = (const float*)d_in[4];
    const float* ph_w = (const float*)d_in[5];
    const float* ph_b = (const float*)d_in[6];
    const float* w_w  = (const float*)d_in[7];
    const float* w_b  = (const float*)d_in[8];
    const float* bn_g = (const float*)d_in[9];
    const float* bn_b = (const float*)d_in[10];
    const float* bn_m = (const float*)d_in[11];
    const float* bn_v = (const float*)d_in[12];
    float* out = (float*)d_out;

    _Float16* xT   = (_Float16*)d_ws;                      // 8*4096*512 = 32 MB
    _Float16* wAll = xT + (size_t)B_ * N_ * C_;            // 768*512
    _Float16* w16  = wAll + 768 * 512;                     // 512*256
    _Float16* thT  = w16 + 512 * 256;                      // 16 MB
    _Float16* phT  = thT + (size_t)B_ * N_ * CI_;          // 4 MB
    _Float16* g16  = phT + (size_t)B_ * M_ * CI_;          // 4 MB
    _Float16* y16  = g16 + (size_t)B_ * M_ * CI_;          // 16 MB (total ~76.5 MB)

    wconv_kernel<<<2048, 256, 0, stream>>>(g_w, th_w, ph_w, w_w, wAll, w16);
    xt_kernel<<<dim3(64, 8, 8), 256, 0, stream>>>(x, xT);
    proj_kernel<<<dim3(32, 12, 8), 256, 0, stream>>>(xT, wAll, g_b, th_b, ph_b,
                                                     thT, phT, g16);
    attn_kernel<<<dim3(64, 8), 256, 0, stream>>>(thT, phT, g16, y16);
    out_kernel<<<dim3(32, 8, 8), 256, 0, stream>>>(y16, w16, w_b, bn_g, bn_b, bn_m, bn_v,
                                                   x, out);
}